// Round 4
// baseline (164.112 us; speedup 1.0000x reference)
//
#include <hip/hip_runtime.h>
#include <hip/hip_bf16.h>

typedef __attribute__((ext_vector_type(8))) short short8;
typedef __attribute__((ext_vector_type(4))) float f32x4;

__device__ __forceinline__ unsigned short f2bf(float x) {
    unsigned int u = __float_as_uint(x);
    unsigned int lsb = (u >> 16) & 1u;
    u += 0x7fffu + lsb;                    // round-to-nearest-even
    return (unsigned short)(u >> 16);
}

__device__ __forceinline__ float bf2f(unsigned int b16) {
    return __uint_as_float(b16 << 16);
}

__device__ __forceinline__ short8 pack8(f32x4 a, f32x4 b) {
    short8 r;
    r[0] = (short)f2bf(a.x); r[1] = (short)f2bf(a.y);
    r[2] = (short)f2bf(a.z); r[3] = (short)f2bf(a.w);
    r[4] = (short)f2bf(b.x); r[5] = (short)f2bf(b.y);
    r[6] = (short)f2bf(b.z); r[7] = (short)f2bf(b.w);
    return r;
}

// Standalone init (fallback path): out[n][c] = bias[c]
__global__ __launch_bounds__(256) void k_init(const float* __restrict__ bias,
                                              float* __restrict__ out, long total4) {
    long i4 = (long)blockIdx.x * 256 + threadIdx.x;
    if (i4 < total4) {
        const f32x4* b4 = (const f32x4*)bias;
        ((f32x4*)out)[i4] = b4[i4 & 15];
    }
}

// Fused: blocks [0,gblocks) compute G = (feat @ W.T) in bf16 via MFMA;
// blocks [gblocks, ...) broadcast bias into out (float4, nontemporal).
__global__ __launch_bounds__(256) void k_setup(const float* __restrict__ feat,
                                               const float* __restrict__ W,
                                               const float* __restrict__ bias,
                                               unsigned short* __restrict__ G,
                                               float* __restrict__ out,
                                               int N, int gblocks) {
    if ((int)blockIdx.x >= gblocks) {
        long i4 = (long)(blockIdx.x - gblocks) * 256 + threadIdx.x;
        long total4 = (long)N * 16;            // N*64 floats / 4
        if (i4 < total4) {
            const f32x4* b4 = (const f32x4*)bias;
            f32x4 v = b4[i4 & 15];
            __builtin_nontemporal_store(v, (f32x4*)out + i4);
        }
        return;
    }

    int wave = blockIdx.x * 4 + (threadIdx.x >> 6);
    int lane = threadIdx.x & 63;
    int m0 = wave * 16;
    if (m0 >= N) return;
    int n = lane & 15;
    int quad = lane >> 4;

    // B fragments: B[k][c0+n] = W[c0+n][k]; k = ks*32 + quad*8 + j
    short8 bf[4][2];
#pragma unroll
    for (int ct = 0; ct < 4; ++ct)
#pragma unroll
        for (int ks = 0; ks < 2; ++ks) {
            const f32x4* wp = (const f32x4*)(W + (size_t)(ct * 16 + n) * 64 + ks * 32 + quad * 8);
            f32x4 w0 = wp[0];
            f32x4 w1 = wp[1];
            bf[ct][ks] = pack8(w0, w1);
        }

    // A fragments: A[m0+n][k]  (nontemporal: feat read exactly once)
    int mrow = m0 + n; if (mrow >= N) mrow = N - 1;
    short8 af[2];
#pragma unroll
    for (int ks = 0; ks < 2; ++ks) {
        const f32x4* ap = (const f32x4*)(feat + (size_t)mrow * 64 + ks * 32 + quad * 8);
        f32x4 a0 = __builtin_nontemporal_load(ap);
        f32x4 a1 = __builtin_nontemporal_load(ap + 1);
        af[ks] = pack8(a0, a1);
    }

    f32x4 acc[4];
#pragma unroll
    for (int ct = 0; ct < 4; ++ct) {
        acc[ct] = (f32x4){0.f, 0.f, 0.f, 0.f};
#pragma unroll
        for (int ks = 0; ks < 2; ++ks)
            acc[ct] = __builtin_amdgcn_mfma_f32_16x16x32_bf16(af[ks], bf[ct][ks], acc[ct], 0, 0, 0);
    }

    // D layout: col = lane&15 (=n), row = quad*4 + reg. G stays cached (L2) —
    // spmm gathers it next.
#pragma unroll
    for (int ct = 0; ct < 4; ++ct)
#pragma unroll
        for (int r = 0; r < 4; ++r) {
            int rowm = m0 + quad * 4 + r;
            if (rowm < N)
                G[(size_t)rowm * 64 + ct * 16 + n] = f2bf(acc[ct][r]);
        }
}

// Flush one row's accumulator: combine the two half-wave partials (they hold
// the same channel pair (2s, 2s+1) for different edges of the same row), then
// lanes 0-31 issue the atomics.
__device__ __forceinline__ void flush_row(float* __restrict__ out, int row,
                                          int s, int h, float a0, float a1) {
    a0 += __shfl_xor(a0, 32, 64);
    a1 += __shfl_xor(a1, 32, 64);
    if (h == 0) {
        float* p = out + ((size_t)(unsigned)row << 6) + (s << 1);
        atomicAdd(p, a0);
        atomicAdd(p + 1, a1);
    }
}

// SpMM: out[row] += val * G[col]. Sorted rows.
// 2 edges per gather: lanes 0-31 = even edge, 32-63 = odd edge; each lane
// loads a dword of G (2 bf16 channels) -> 1 VMEM instr / 2 edges.
// Metadata readlane-broadcast -> scalar row bookkeeping.
__global__ __launch_bounds__(256) void k_spmm(const unsigned* __restrict__ Gd,
                                              const int* __restrict__ erow,
                                              const int* __restrict__ ecol,
                                              const float* __restrict__ evalv,
                                              float* __restrict__ out,
                                              int E, int cpw) {
    int wave = blockIdx.x * 4 + (threadIdx.x >> 6);
    int lane = threadIdx.x & 63;
    int h = lane >> 5;          // half: 0 = even edge of pair, 1 = odd
    int s = lane & 31;          // channel pair index: channels 2s, 2s+1
    long base0 = (long)wave * cpw * 64;
    if (base0 >= E) return;

    int cur = __builtin_amdgcn_readfirstlane(erow[base0]);
    float acc0 = 0.f, acc1 = 0.f;

    for (int ch = 0; ch < cpw; ++ch) {
        long base = base0 + (long)ch * 64;
        if (base >= E) break;
        long idx = base + lane;
        long cidx = idx < E ? idx : (long)(E - 1);
        int rv = __builtin_nontemporal_load(erow + cidx);
        int cv = __builtin_nontemporal_load(ecol + cidx);
        float vf = (idx < E) ? __builtin_nontemporal_load(evalv + cidx) : 0.f;
        int vv = __float_as_int(vf);

#pragma unroll
        for (int j0 = 0; j0 < 32; j0 += 16) {
            unsigned g[16];
            // issue 16 paired gathers (covers 32 edges), then consume
#pragma unroll
            for (int u = 0; u < 16; ++u) {
                int p = j0 + u;
                int c0 = __builtin_amdgcn_readlane(cv, 2 * p);
                int c1 = __builtin_amdgcn_readlane(cv, 2 * p + 1);
                int cc = h ? c1 : c0;
                g[u] = Gd[(size_t)(unsigned)cc * 32u + (unsigned)s];
            }
#pragma unroll
            for (int u = 0; u < 16; ++u) {
                int p = j0 + u;
                int r0 = __builtin_amdgcn_readlane(rv, 2 * p);      // SGPR
                int r1 = __builtin_amdgcn_readlane(rv, 2 * p + 1);  // SGPR
                float v0 = __int_as_float(__builtin_amdgcn_readlane(vv, 2 * p));
                float v1 = __int_as_float(__builtin_amdgcn_readlane(vv, 2 * p + 1));
                float g0 = bf2f(g[u] & 0xffffu);
                float g1 = bf2f(g[u] >> 16);
                if (r0 == cur && r1 == cur) {                        // scalar fast path
                    float vh = h ? v1 : v0;
                    acc0 = fmaf(vh, g0, acc0);
                    acc1 = fmaf(vh, g1, acc1);
                } else {                                             // row boundary in pair
                    if (r0 != cur) {
                        flush_row(out, cur, s, h, acc0, acc1);
                        acc0 = 0.f; acc1 = 0.f; cur = r0;
                    }
                    float ve0 = (h == 0) ? v0 : 0.f;                 // add even edge only
                    acc0 = fmaf(ve0, g0, acc0);
                    acc1 = fmaf(ve0, g1, acc1);
                    if (r1 != cur) {
                        flush_row(out, cur, s, h, acc0, acc1);
                        acc0 = 0.f; acc1 = 0.f; cur = r1;
                    }
                    float ve1 = (h == 1) ? v1 : 0.f;                 // add odd edge only
                    acc0 = fmaf(ve1, g0, acc0);
                    acc1 = fmaf(ve1, g1, acc1);
                }
            }
        }
    }
    flush_row(out, cur, s, h, acc0, acc1);
}

// Fallback if ws too small: fused f32 gather + shfl transform at flush.
__global__ __launch_bounds__(256) void k_fused(const float* __restrict__ feat,
                                               const int* __restrict__ erow,
                                               const int* __restrict__ ecol,
                                               const float* __restrict__ evalv,
                                               const float* __restrict__ W,
                                               float* __restrict__ out,
                                               int E, int epw) {
    __shared__ float Wt[64 * 64];
    for (int i = threadIdx.x; i < 4096; i += 256) {
        int c = i >> 6, f = i & 63;
        Wt[f * 64 + c] = W[i];
    }
    __syncthreads();

    int wave = blockIdx.x * 4 + (threadIdx.x >> 6);
    int lane = threadIdx.x & 63;
    long e0 = (long)wave * epw;
    if (e0 >= E) return;
    long e1 = e0 + epw; if (e1 > E) e1 = E;

    int cur = erow[e0];
    float acc = 0.f;
    for (long e = e0; e < e1; ++e) {
        int r = erow[e];
        int c = ecol[e];
        float v = evalv[e];
        float g = feat[((size_t)c << 6) | lane];
        if (r != cur) {
            float res = 0.f;
#pragma unroll
            for (int f = 0; f < 64; ++f)
                res += __shfl(acc, f, 64) * Wt[f * 64 + lane];
            atomicAdd(out + ((size_t)cur << 6) + lane, res);
            acc = 0.f;
            cur = r;
        }
        acc += v * g;
    }
    {
        float res = 0.f;
#pragma unroll
        for (int f = 0; f < 64; ++f)
            res += __shfl(acc, f, 64) * Wt[f * 64 + lane];
        atomicAdd(out + ((size_t)cur << 6) + lane, res);
    }
}

extern "C" void kernel_launch(void* const* d_in, const int* in_sizes, int n_in,
                              void* d_out, int out_size, void* d_ws, size_t ws_size,
                              hipStream_t stream) {
    const float* feat  = (const float*)d_in[0];
    const int*   erow  = (const int*)d_in[1];
    const int*   ecol  = (const int*)d_in[2];
    const float* evalv = (const float*)d_in[3];
    const float* W     = (const float*)d_in[4];
    const float* bias  = (const float*)d_in[5];
    float* out = (float*)d_out;

    int N = in_sizes[0] / 64;
    int E = in_sizes[1];

    size_t need = (size_t)N * 64 * sizeof(unsigned short);
    if (ws_size >= need) {
        unsigned short* G = (unsigned short*)d_ws;
        int tiles = (N + 15) / 16;
        int gblocks = (tiles + 3) / 4;
        long total4 = (long)N * 16;
        int iblocks = (int)((total4 + 255) / 256);
        k_setup<<<gblocks + iblocks, 256, 0, stream>>>(feat, W, bias, G, out, N, gblocks);

        const int cpw = 2;                       // 128 edges/wave -> 12500 waves (~8/SIMD)
        int nchunks = (E + 63) / 64;
        int nwaves = (nchunks + cpw - 1) / cpw;
        int nblocks = (nwaves + 3) / 4;
        k_spmm<<<nblocks, 256, 0, stream>>>((const unsigned*)G, erow, ecol, evalv, out, E, cpw);
    } else {
        long total4 = (long)N * 16;
        k_init<<<(int)((total4 + 255) / 256), 256, 0, stream>>>(bias, out, total4);
        int epw = (E + 8191) / 8192;
        if (epw < 32) epw = 32;
        int nwaves = (E + epw - 1) / epw;
        int nblocks = (nwaves + 3) / 4;
        k_fused<<<nblocks, 256, 0, stream>>>(feat, erow, ecol, evalv, W, out, E, epw);
    }
}

// Round 5
// 142.477 us; speedup vs baseline: 1.1519x; 1.1519x over previous
//
#include <hip/hip_runtime.h>
#include <hip/hip_bf16.h>

typedef __attribute__((ext_vector_type(8))) short short8;
typedef __attribute__((ext_vector_type(4))) float f32x4;

__device__ __forceinline__ unsigned short f2bf(float x) {
    unsigned int u = __float_as_uint(x);
    unsigned int lsb = (u >> 16) & 1u;
    u += 0x7fffu + lsb;                    // round-to-nearest-even
    return (unsigned short)(u >> 16);
}

__device__ __forceinline__ float bf2f(unsigned int b16) {
    return __uint_as_float(b16 << 16);
}

__device__ __forceinline__ short8 pack8(f32x4 a, f32x4 b) {
    short8 r;
    r[0] = (short)f2bf(a.x); r[1] = (short)f2bf(a.y);
    r[2] = (short)f2bf(a.z); r[3] = (short)f2bf(a.w);
    r[4] = (short)f2bf(b.x); r[5] = (short)f2bf(b.y);
    r[6] = (short)f2bf(b.z); r[7] = (short)f2bf(b.w);
    return r;
}

// Standalone init (fallback path): out[n][c] = bias[c]
__global__ __launch_bounds__(256) void k_init(const float* __restrict__ bias,
                                              float* __restrict__ out, long total4) {
    long i4 = (long)blockIdx.x * 256 + threadIdx.x;
    if (i4 < total4) {
        const f32x4* b4 = (const f32x4*)bias;
        ((f32x4*)out)[i4] = b4[i4 & 15];
    }
}

// Fused: blocks [0,gblocks) compute G = (feat @ W.T) in bf16 via MFMA;
// blocks [gblocks, ...) broadcast bias into out.
// NOTE: out init must be a PLAIN store — NT store streamed it to HBM and made
// every later atomic flush RMW against HBM (R4: WRITE_SIZE doubled, +22 us).
__global__ __launch_bounds__(256) void k_setup(const float* __restrict__ feat,
                                               const float* __restrict__ W,
                                               const float* __restrict__ bias,
                                               unsigned short* __restrict__ G,
                                               float* __restrict__ out,
                                               int N, int gblocks) {
    if ((int)blockIdx.x >= gblocks) {
        long i4 = (long)(blockIdx.x - gblocks) * 256 + threadIdx.x;
        long total4 = (long)N * 16;            // N*64 floats / 4
        if (i4 < total4) {
            const f32x4* b4 = (const f32x4*)bias;
            ((f32x4*)out)[i4] = b4[i4 & 15];   // plain store: stay dirty in L2
        }
        return;
    }

    int wave = blockIdx.x * 4 + (threadIdx.x >> 6);
    int lane = threadIdx.x & 63;
    int m0 = wave * 16;
    if (m0 >= N) return;
    int n = lane & 15;
    int quad = lane >> 4;

    // B fragments: B[k][c0+n] = W[c0+n][k]; k = ks*32 + quad*8 + j
    short8 bf[4][2];
#pragma unroll
    for (int ct = 0; ct < 4; ++ct)
#pragma unroll
        for (int ks = 0; ks < 2; ++ks) {
            const f32x4* wp = (const f32x4*)(W + (size_t)(ct * 16 + n) * 64 + ks * 32 + quad * 8);
            f32x4 w0 = wp[0];
            f32x4 w1 = wp[1];
            bf[ct][ks] = pack8(w0, w1);
        }

    // A fragments: A[m0+n][k]  (NT load: feat read exactly once)
    int mrow = m0 + n; if (mrow >= N) mrow = N - 1;
    short8 af[2];
#pragma unroll
    for (int ks = 0; ks < 2; ++ks) {
        const f32x4* ap = (const f32x4*)(feat + (size_t)mrow * 64 + ks * 32 + quad * 8);
        f32x4 a0 = __builtin_nontemporal_load(ap);
        f32x4 a1 = __builtin_nontemporal_load(ap + 1);
        af[ks] = pack8(a0, a1);
    }

    f32x4 acc[4];
#pragma unroll
    for (int ct = 0; ct < 4; ++ct) {
        acc[ct] = (f32x4){0.f, 0.f, 0.f, 0.f};
#pragma unroll
        for (int ks = 0; ks < 2; ++ks)
            acc[ct] = __builtin_amdgcn_mfma_f32_16x16x32_bf16(af[ks], bf[ct][ks], acc[ct], 0, 0, 0);
    }

    // D layout: col = lane&15 (=n), row = quad*4 + reg. Plain stores: G is
    // re-read by k_spmm, keep it in L2/L3.
#pragma unroll
    for (int ct = 0; ct < 4; ++ct)
#pragma unroll
        for (int r = 0; r < 4; ++r) {
            int rowm = m0 + quad * 4 + r;
            if (rowm < N)
                G[(size_t)rowm * 64 + ct * 16 + n] = f2bf(acc[ct][r]);
        }
}

// SpMM: out[row] += val * G[col]. Sorted rows.
// Per 64-edge chunk: coalesced metadata loads (NT: single-use stream), then
// readlane-broadcast -> (r,c,v) are SGPRs: scalar flush branch, SGPR gather
// base, contiguous 64-lane gather (2B/lane = one 128B G row per instr).
// 16 gathers issued before first consume -> 16 outstanding VMEM per wave.
__global__ __launch_bounds__(256) void k_spmm(const unsigned short* __restrict__ G,
                                              const int* __restrict__ erow,
                                              const int* __restrict__ ecol,
                                              const float* __restrict__ evalv,
                                              float* __restrict__ out,
                                              int E, int cpw) {
    int wave = blockIdx.x * 4 + (threadIdx.x >> 6);
    int lane = threadIdx.x & 63;
    long base0 = (long)wave * cpw * 64;
    if (base0 >= E) return;

    int cur = __builtin_amdgcn_readfirstlane(erow[base0]);
    float acc = 0.f;

    for (int ch = 0; ch < cpw; ++ch) {
        long base = base0 + (long)ch * 64;
        if (base >= E) break;
        long idx = base + lane;
        long cidx = idx < E ? idx : (long)(E - 1);
        int rv = __builtin_nontemporal_load(erow + cidx);
        int cv = __builtin_nontemporal_load(ecol + cidx);
        float vf = (idx < E) ? __builtin_nontemporal_load(evalv + cidx) : 0.f;
        int vv = __float_as_int(vf);

#pragma unroll
        for (int j0 = 0; j0 < 64; j0 += 16) {
            float g[16];
#pragma unroll
            for (int u = 0; u < 16; ++u) {
                int c = __builtin_amdgcn_readlane(cv, j0 + u);   // SGPR
                g[u] = bf2f(G[((size_t)(unsigned)c << 6) | (unsigned)lane]);
            }
#pragma unroll
            for (int u = 0; u < 16; ++u) {
                int r = __builtin_amdgcn_readlane(rv, j0 + u);   // SGPR
                float v = __int_as_float(__builtin_amdgcn_readlane(vv, j0 + u));
                if (r != cur) {                                   // scalar branch
                    atomicAdd(out + ((size_t)(unsigned)cur << 6) + lane, acc);
                    acc = 0.f;
                    cur = r;
                }
                acc = fmaf(v, g[u], acc);
            }
        }
    }
    atomicAdd(out + ((size_t)(unsigned)cur << 6) + lane, acc);
}

// Fallback if ws too small: fused f32 gather + shfl transform at flush.
__global__ __launch_bounds__(256) void k_fused(const float* __restrict__ feat,
                                               const int* __restrict__ erow,
                                               const int* __restrict__ ecol,
                                               const float* __restrict__ evalv,
                                               const float* __restrict__ W,
                                               float* __restrict__ out,
                                               int E, int epw) {
    __shared__ float Wt[64 * 64];
    for (int i = threadIdx.x; i < 4096; i += 256) {
        int c = i >> 6, f = i & 63;
        Wt[f * 64 + c] = W[i];
    }
    __syncthreads();

    int wave = blockIdx.x * 4 + (threadIdx.x >> 6);
    int lane = threadIdx.x & 63;
    long e0 = (long)wave * epw;
    if (e0 >= E) return;
    long e1 = e0 + epw; if (e1 > E) e1 = E;

    int cur = erow[e0];
    float acc = 0.f;
    for (long e = e0; e < e1; ++e) {
        int r = erow[e];
        int c = ecol[e];
        float v = evalv[e];
        float g = feat[((size_t)c << 6) | lane];
        if (r != cur) {
            float res = 0.f;
#pragma unroll
            for (int f = 0; f < 64; ++f)
                res += __shfl(acc, f, 64) * Wt[f * 64 + lane];
            atomicAdd(out + ((size_t)cur << 6) + lane, res);
            acc = 0.f;
            cur = r;
        }
        acc += v * g;
    }
    {
        float res = 0.f;
#pragma unroll
        for (int f = 0; f < 64; ++f)
            res += __shfl(acc, f, 64) * Wt[f * 64 + lane];
        atomicAdd(out + ((size_t)cur << 6) + lane, res);
    }
}

extern "C" void kernel_launch(void* const* d_in, const int* in_sizes, int n_in,
                              void* d_out, int out_size, void* d_ws, size_t ws_size,
                              hipStream_t stream) {
    const float* feat  = (const float*)d_in[0];
    const int*   erow  = (const int*)d_in[1];
    const int*   ecol  = (const int*)d_in[2];
    const float* evalv = (const float*)d_in[3];
    const float* W     = (const float*)d_in[4];
    const float* bias  = (const float*)d_in[5];
    float* out = (float*)d_out;

    int N = in_sizes[0] / 64;
    int E = in_sizes[1];

    size_t need = (size_t)N * 64 * sizeof(unsigned short);
    if (ws_size >= need) {
        unsigned short* G = (unsigned short*)d_ws;
        int tiles = (N + 15) / 16;
        int gblocks = (tiles + 3) / 4;
        long total4 = (long)N * 16;
        int iblocks = (int)((total4 + 255) / 256);
        k_setup<<<gblocks + iblocks, 256, 0, stream>>>(feat, W, bias, G, out, N, gblocks);

        const int cpw = 2;                       // 128 edges/wave -> 12500 waves (~8+/SIMD)
        int nchunks = (E + 63) / 64;
        int nwaves = (nchunks + cpw - 1) / cpw;
        int nblocks = (nwaves + 3) / 4;
        k_spmm<<<nblocks, 256, 0, stream>>>(G, erow, ecol, evalv, out, E, cpw);
    } else {
        long total4 = (long)N * 16;
        k_init<<<(int)((total4 + 255) / 256), 256, 0, stream>>>(bias, out, total4);
        int epw = (E + 8191) / 8192;
        if (epw < 32) epw = 32;
        int nwaves = (E + epw - 1) / epw;
        int nblocks = (nwaves + 3) / 4;
        k_fused<<<nblocks, 256, 0, stream>>>(feat, erow, ecol, evalv, W, out, E, epw);
    }
}